// Round 18
// baseline (3053.647 us; speedup 1.0000x reference)
//
#include <hip/hip_runtime.h>
#include <hip/hip_bf16.h>

#define TT 2048
#define BB 32
#define DD 256
#define HH 256
#define GG 768   // 3*H

#define KT_LDS 3   // kt groups resident in LDS (144 KB)
#define KT_STR 5   // kt groups streamed from L2 each step (240 KB)

typedef _Float16 half2_t __attribute__((ext_vector_type(2)));
typedef _Float16 f16x8 __attribute__((ext_vector_type(8)));
typedef float    f32x4 __attribute__((ext_vector_type(4)));
typedef unsigned int u32x4 __attribute__((ext_vector_type(4)));

// ---------- helpers for fp32/bf16 workspace storage of gi ----------
__device__ inline float ldgi(const float* p) { return *p; }
__device__ inline float ldgi(const __hip_bfloat16* p) { return __bfloat162float(*p); }
__device__ inline void stgi(float* p, float v) { *p = v; }
__device__ inline void stgi(__hip_bfloat16* p, float v) { *p = __float2bfloat16(v); }

// ---------- pack w_hh [768][256] f32 into kt-major MFMA B-fragments --------
// uint4 element e = (kt*48 + wv*6 + nt)*64 + l, u32 component r:
//   n = wv*96 + nt*16 + (l&15)
//   k = kt*32 + (l>>4)*8 + 2r   (u32 = f16 pair {k, k+1})
__global__ __launch_bounds__(256)
void pack_w(const float* __restrict__ w, unsigned int* __restrict__ wf) {
    int i = blockIdx.x * 256 + threadIdx.x;  // 0 .. 98303
    int r   = i & 3;
    int l   = (i >> 2) & 63;
    int e   = i >> 8;             // kt*48 + wv*6 + nt
    int nt6 = e % 48;
    int kt  = e / 48;
    int wv  = nt6 / 6, nt = nt6 % 6;
    int n = wv * 96 + nt * 16 + (l & 15);
    int k = kt * 32 + (l >> 4) * 8 + 2 * r;
    float a = w[(size_t)n * DD + k];
    float b = w[(size_t)n * DD + k + 1];
    half2_t h = {(_Float16)a, (_Float16)b};
    wf[i] = __builtin_bit_cast(unsigned int, h);
}

// ---------- gi = seq @ w_ih^T + b_ih via f16 MFMA (verified r10) ----------
template <typename GiT>
__global__ __launch_bounds__(256)
void gemm_gi_mfma(const float* __restrict__ A,     // [M][256] f32
                  const float* __restrict__ W,     // [768][256] f32
                  const float* __restrict__ bias,  // [768]
                  GiT* __restrict__ C)              // [M][768]
{
    __shared__ __align__(16) _Float16 Asl[128][40];
    __shared__ __align__(16) _Float16 Bsl[128][40];

    const int tid = threadIdx.x;
    const int wv  = tid >> 6;
    const int l   = tid & 63;
    const int wm  = (wv & 1) * 64;
    const int wn  = (wv >> 1) * 64;
    const size_t bm = (size_t)blockIdx.y * 128;
    const int    bn = blockIdx.x * 128;

    const int lr = tid >> 3;
    const int lc = (tid & 7) * 4;

    f32x4 acc[4][4] = {};

    for (int kt = 0; kt < 256; kt += 32) {
#pragma unroll
        for (int rr = 0; rr < 128; rr += 32) {
            float4 av = *(const float4*)&A[(bm + lr + rr) * DD + kt + lc];
            half2_t p0 = {(_Float16)av.x, (_Float16)av.y};
            half2_t p1 = {(_Float16)av.z, (_Float16)av.w};
            uint2 pk = {__builtin_bit_cast(unsigned int, p0),
                        __builtin_bit_cast(unsigned int, p1)};
            *(uint2*)&Asl[lr + rr][lc] = pk;
        }
#pragma unroll
        for (int rr = 0; rr < 128; rr += 32) {
            float4 bv = *(const float4*)&W[(size_t)(bn + lr + rr) * DD + kt + lc];
            half2_t p0 = {(_Float16)bv.x, (_Float16)bv.y};
            half2_t p1 = {(_Float16)bv.z, (_Float16)bv.w};
            uint2 pk = {__builtin_bit_cast(unsigned int, p0),
                        __builtin_bit_cast(unsigned int, p1)};
            *(uint2*)&Bsl[lr + rr][lc] = pk;
        }
        __syncthreads();

        f16x8 af[4], bf[4];
#pragma unroll
        for (int i = 0; i < 4; ++i) {
            af[i] = *(const f16x8*)&Asl[wm + i * 16 + (l & 15)][(l >> 4) * 8];
            bf[i] = *(const f16x8*)&Bsl[wn + i * 16 + (l & 15)][(l >> 4) * 8];
        }
#pragma unroll
        for (int mi = 0; mi < 4; ++mi)
#pragma unroll
            for (int ni = 0; ni < 4; ++ni)
                acc[mi][ni] = __builtin_amdgcn_mfma_f32_16x16x32_f16(
                    af[mi], bf[ni], acc[mi][ni], 0, 0, 0);
        __syncthreads();
    }

    const int crow = (l >> 4) * 4;
    const int ccol = l & 15;
#pragma unroll
    for (int ni = 0; ni < 4; ++ni) {
        int n = bn + wn + ni * 16 + ccol;
        float bs = bias[n];
#pragma unroll
        for (int mi = 0; mi < 4; ++mi) {
#pragma unroll
            for (int q = 0; q < 4; ++q) {
                size_t m = bm + wm + mi * 16 + crow + q;
                stgi(&C[m * GG + n], acc[mi][ni][q] + bs);
            }
        }
    }
}

// ---------- MFMA scan: LDS-resident + asm-streamed weight split ----------
// r17 post-mortem: the split was right (L2-return ~116B/cyc and LDS ~85B/cyc
// are parallel pipes) but the compiler sank the 30 streamed loads to their
// uses (VGPR_Count=120), serializing L2 latency. Fix: volatile inline-asm
// global_load_dwordx4 (cannot be sunk/remat'd; 120 regs held only WITHIN a
// step — fits the 256 budget), sched_barrier(0) pinning issue to loop top,
// and counted s_waitcnt vmcnt(24/18/12/6/0) + sched_barrier(0) before each
// streamed kt-group's MFMAs (rule: hipcc hoists reg-only MFMA past asm
// waitcnt without the sched fence). vmcnt counts are safe for any placement
// of the 3 ordinary gi loads: with 33 outstanding, vmcnt(24-6s) implies
// >= 9+6s oldest complete, which always covers stream loads 0..6s+5.
template <typename GiT>
__global__ void
__attribute__((amdgpu_flat_work_group_size(512, 512), amdgpu_waves_per_eu(2, 2)))
gru_scan_mfma(const GiT* __restrict__ gi,          // [T*B][768]
              const int* __restrict__ mask,         // [T*B]
              const float* __restrict__ h0,         // [B][256]
              const unsigned int* __restrict__ wf,  // packed B-fragments
              const float* __restrict__ b_hh,       // [768]
              float* __restrict__ out,              // [T*B][256]
              float* __restrict__ hfin)             // [B][256]
{
    const int b   = blockIdx.x;
    const int tid = threadIdx.x;   // 0..511
    const int wv  = tid >> 6;      // 0..7
    const int l   = tid & 63;

    __shared__ u32x4 wlds[KT_LDS * 48 * 64];            // 147456 B
    __shared__ __align__(16) _Float16 hhalf[HH];        // 512 B
    __shared__ float gh_lds[GG];                        // 3072 B
    __shared__ unsigned long long mbits[TT / 64];       // 256 B

    const u32x4* wp4 = (const u32x4*)wf;

    // --- one-time: stage kt groups 0..KT_LDS-1 into LDS (coalesced) ---
    for (int i = tid; i < KT_LDS * 48 * 64; i += 512)
        wlds[i] = wp4[i];

    // --- one-time: mask -> bitmask ---
    if (tid < TT / 64) {
        unsigned long long v = 0;
        for (int s = 0; s < 64; ++s)
            v |= (mask[(tid * 64 + s) * BB + b] ? 1ull : 0ull) << s;
        mbits[tid] = v;
    }

    float h_r = 0.f, bh0 = 0.f, bh1 = 0.f, bh2 = 0.f;
    if (tid < HH) {
        h_r = h0[b * HH + tid];
        hhalf[tid] = (_Float16)h_r;
        bh0 = b_hh[tid];
        bh1 = b_hh[tid + HH];
        bh2 = b_hh[tid + 2 * HH];
    }
    __syncthreads();

    // A-operand broadcast source: 16-lane group g=(l>>4) reads h[kt*32+g*8..]
    const _Float16* abase = hhalf + (l >> 4) * 8;
    // per-wave fragment bases
    const u32x4* wstr  = wp4 + (size_t)(KT_LDS * 48 + wv * 6) * 64 + l;
    const u32x4* wldsb = wlds + (size_t)(wv * 6) * 64 + l;

    for (int ts = 0; ts < TT; ++ts) {
        if ((mbits[ts >> 6] >> (ts & 63)) & 1ull) {
            // --- issue all 30 streamed loads NOW (volatile: un-sinkable) ---
            u32x4 ws[KT_STR][6];
#pragma unroll
            for (int s = 0; s < KT_STR; ++s)
#pragma unroll
                for (int nt = 0; nt < 6; ++nt)
                    asm volatile("global_load_dwordx4 %0, %1, off"
                                 : "=v"(ws[s][nt])
                                 : "v"(wstr + (size_t)(s * 48 + nt) * 64));
            __builtin_amdgcn_sched_barrier(0);  // pin issues to loop top

            // gi loads (ordinary; consumed in the gate phase)
            float ir = 0.f, iz = 0.f, inn = 0.f;
            if (tid < HH) {
                const GiT* gtb = gi + ((size_t)ts * BB + b) * GG;
                ir  = ldgi(gtb + tid);
                iz  = ldgi(gtb + tid + HH);
                inn = ldgi(gtb + tid + 2 * HH);
            }

            // --- LDS-resident MFMAs (run while the stream drains) ---
            f32x4 acc[6] = {};
#pragma unroll
            for (int kt = 0; kt < KT_LDS; ++kt) {
                f16x8 a = *(const f16x8*)(abase + kt * 32);
#pragma unroll
                for (int nt = 0; nt < 6; ++nt) {
                    u32x4 wv4 = wldsb[(size_t)(kt * 48 + nt) * 64];
                    acc[nt] = __builtin_amdgcn_mfma_f32_16x16x32_f16(
                        a, __builtin_bit_cast(f16x8, wv4), acc[nt], 0, 0, 0);
                }
            }

            // --- streamed MFMAs, consumed per-group behind counted vmcnt ---
#define CONSUME_GROUP(S, VMCNT_STR)                                          \
            {                                                                \
                asm volatile("s_waitcnt " VMCNT_STR ::: "memory");           \
                __builtin_amdgcn_sched_barrier(0);                           \
                f16x8 a = *(const f16x8*)(abase + (KT_LDS + (S)) * 32);      \
                _Pragma("unroll")                                            \
                for (int nt = 0; nt < 6; ++nt)                               \
                    acc[nt] = __builtin_amdgcn_mfma_f32_16x16x32_f16(        \
                        a, __builtin_bit_cast(f16x8, ws[(S)][nt]), acc[nt],  \
                        0, 0, 0);                                            \
            }
            CONSUME_GROUP(0, "vmcnt(24)")
            CONSUME_GROUP(1, "vmcnt(18)")
            CONSUME_GROUP(2, "vmcnt(12)")
            CONSUME_GROUP(3, "vmcnt(6)")
            CONSUME_GROUP(4, "vmcnt(0)")
#undef CONSUME_GROUP

            // C row 0 (all rows equal): lanes 0-15, reg 0
            if (l < 16) {
#pragma unroll
                for (int nt = 0; nt < 6; ++nt)
                    gh_lds[wv * 96 + nt * 16 + l] = acc[nt][0];
            }
            __syncthreads();  // gh visible; hhalf reads done

            if (tid < HH) {
                float hr = gh_lds[tid] + bh0;
                float hz = gh_lds[tid + HH] + bh1;
                float hn = gh_lds[tid + 2 * HH] + bh2;
                float r = 1.f / (1.f + __expf(-(ir + hr)));
                float z = 1.f / (1.f + __expf(-(iz + hz)));
                float e = __expf(2.f * (inn + r * hn));
                float n = 1.f - 2.f / (e + 1.f);
                float ht = (1.f - z) * n + z * h_r;
                out[((size_t)ts * BB + b) * HH + tid] = ht;
                h_r = ht;
                hhalf[tid] = (_Float16)ht;
            }
            __syncthreads();  // h update visible before next GEMV
        } else {
            // masked: h unchanged, output row exactly zero; no barriers
            if (tid < HH)
                out[((size_t)ts * BB + b) * HH + tid] = 0.f;
        }
    }
    if (tid < HH) hfin[b * HH + tid] = h_r;
}

extern "C" void kernel_launch(void* const* d_in, const int* in_sizes, int n_in,
                              void* d_out, int out_size, void* d_ws, size_t ws_size,
                              hipStream_t stream) {
    const float* seq  = (const float*)d_in[0];
    const int*   mask = (const int*)  d_in[1];
    const float* h0   = (const float*)d_in[2];
    const float* w_ih = (const float*)d_in[3];
    const float* w_hh = (const float*)d_in[4];
    const float* b_ih = (const float*)d_in[5];
    const float* b_hh = (const float*)d_in[6];

    float* out  = (float*)d_out;
    float* hfin = out + (size_t)TT * BB * HH;

    // workspace layout: [wf: 98304 u32][gi: T*B*768 f32 (or bf16 fallback)]
    const size_t wf_elems = (size_t)128 * GG;  // 98304
    unsigned int* wf = (unsigned int*)d_ws;
    const size_t gi_elems = (size_t)TT * BB * GG;
    const size_t need_f32 = wf_elems * 4 + gi_elems * 4;

    pack_w<<<(int)(wf_elems / 256), 256, 0, stream>>>(w_hh, wf);

    dim3 ggrid(GG / 128, (TT * BB) / 128);  // 6 x 512
    if (ws_size >= need_f32) {
        float* gip = (float*)d_ws + wf_elems;
        gemm_gi_mfma<float><<<ggrid, 256, 0, stream>>>(seq, w_ih, b_ih, gip);
        gru_scan_mfma<float><<<BB, 512, 0, stream>>>(gip, mask, h0, wf, b_hh,
                                                     out, hfin);
    } else {
        __hip_bfloat16* gip = (__hip_bfloat16*)((float*)d_ws + wf_elems);
        gemm_gi_mfma<__hip_bfloat16><<<ggrid, 256, 0, stream>>>(seq, w_ih, b_ih, gip);
        gru_scan_mfma<__hip_bfloat16><<<BB, 512, 0, stream>>>(gip, mask, h0, wf,
                                                              b_hh, out, hfin);
    }
}

// Round 19
// 1500.519 us; speedup vs baseline: 2.0351x; 2.0351x over previous
//
#include <hip/hip_runtime.h>
#include <hip/hip_bf16.h>

#define TT 2048
#define BB 32
#define DD 256
#define HH 256
#define GG 768   // 3*H

typedef _Float16 half2_t __attribute__((ext_vector_type(2)));
typedef _Float16 f16x8 __attribute__((ext_vector_type(8)));
typedef float    f32x4 __attribute__((ext_vector_type(4)));
typedef unsigned int u32x4 __attribute__((ext_vector_type(4)));

// ---------- helpers for fp32/bf16 workspace storage of gi ----------
__device__ inline float ldgi(const float* p) { return *p; }
__device__ inline float ldgi(const __hip_bfloat16* p) { return __bfloat162float(*p); }
__device__ inline void stgi(float* p, float v) { *p = v; }
__device__ inline void stgi(__hip_bfloat16* p, float v) { *p = __float2bfloat16(v); }

// ---------- pack w_hh [768][256] f32 into per-wave MFMA B-fragments ----------
// flat u32 index: (((wv*6+nt)*8+kt)*64+l)*4+r
//   n = wv*96 + nt*16 + (l&15)
//   k = kt*32 + (l>>4)*8 + 2r   (u32 = f16 pair {k, k+1}, low half first)
__global__ __launch_bounds__(256)
void pack_w(const float* __restrict__ w, unsigned int* __restrict__ wf) {
    int idx = blockIdx.x * 256 + threadIdx.x;  // 0 .. 98303
    int r    = idx & 3;
    int l    = (idx >> 2) & 63;
    int kt   = (idx >> 8) & 7;
    int rest = idx >> 11;            // wv*6 + nt, 0..47
    int nt = rest % 6, wv = rest / 6;
    int n = wv * 96 + nt * 16 + (l & 15);
    int k = kt * 32 + (l >> 4) * 8 + 2 * r;
    float a = w[(size_t)n * DD + k];
    float b = w[(size_t)n * DD + k + 1];
    half2_t h = {(_Float16)a, (_Float16)b};
    wf[idx] = __builtin_bit_cast(unsigned int, h);
}

// ---------- gi = seq @ w_ih^T + b_ih via f16 MFMA (verified r10) ----------
template <typename GiT>
__global__ __launch_bounds__(256)
void gemm_gi_mfma(const float* __restrict__ A,     // [M][256] f32
                  const float* __restrict__ W,     // [768][256] f32
                  const float* __restrict__ bias,  // [768]
                  GiT* __restrict__ C)              // [M][768]
{
    __shared__ __align__(16) _Float16 Asl[128][40];
    __shared__ __align__(16) _Float16 Bsl[128][40];

    const int tid = threadIdx.x;
    const int wv  = tid >> 6;
    const int l   = tid & 63;
    const int wm  = (wv & 1) * 64;
    const int wn  = (wv >> 1) * 64;
    const size_t bm = (size_t)blockIdx.y * 128;
    const int    bn = blockIdx.x * 128;

    const int lr = tid >> 3;
    const int lc = (tid & 7) * 4;

    f32x4 acc[4][4] = {};

    for (int kt = 0; kt < 256; kt += 32) {
#pragma unroll
        for (int rr = 0; rr < 128; rr += 32) {
            float4 av = *(const float4*)&A[(bm + lr + rr) * DD + kt + lc];
            half2_t p0 = {(_Float16)av.x, (_Float16)av.y};
            half2_t p1 = {(_Float16)av.z, (_Float16)av.w};
            uint2 pk = {__builtin_bit_cast(unsigned int, p0),
                        __builtin_bit_cast(unsigned int, p1)};
            *(uint2*)&Asl[lr + rr][lc] = pk;
        }
#pragma unroll
        for (int rr = 0; rr < 128; rr += 32) {
            float4 bv = *(const float4*)&W[(size_t)(bn + lr + rr) * DD + kt + lc];
            half2_t p0 = {(_Float16)bv.x, (_Float16)bv.y};
            half2_t p1 = {(_Float16)bv.z, (_Float16)bv.w};
            uint2 pk = {__builtin_bit_cast(unsigned int, p0),
                        __builtin_bit_cast(unsigned int, p1)};
            *(uint2*)&Bsl[lr + rr][lc] = pk;
        }
        __syncthreads();

        f16x8 af[4], bf[4];
#pragma unroll
        for (int i = 0; i < 4; ++i) {
            af[i] = *(const f16x8*)&Asl[wm + i * 16 + (l & 15)][(l >> 4) * 8];
            bf[i] = *(const f16x8*)&Bsl[wn + i * 16 + (l & 15)][(l >> 4) * 8];
        }
#pragma unroll
        for (int mi = 0; mi < 4; ++mi)
#pragma unroll
            for (int ni = 0; ni < 4; ++ni)
                acc[mi][ni] = __builtin_amdgcn_mfma_f32_16x16x32_f16(
                    af[mi], bf[ni], acc[mi][ni], 0, 0, 0);
        __syncthreads();
    }

    const int crow = (l >> 4) * 4;
    const int ccol = l & 15;
#pragma unroll
    for (int ni = 0; ni < 4; ++ni) {
        int n = bn + wn + ni * 16 + ccol;
        float bs = bias[n];
#pragma unroll
        for (int mi = 0; mi < 4; ++mi) {
#pragma unroll
            for (int q = 0; q < 4; ++q) {
                size_t m = bm + wm + mi * 16 + crow + q;
                stgi(&C[m * GG + n], acc[mi][ni][q] + bs);
            }
        }
    }
}

// ---------- MFMA scan: 1 batch/block, streamed weights (r14, best) ----------
// The scan is at its per-CU vector-return bandwidth floor: 384 KB of weights
// per unmasked step / ~116 B/cyc = 3310 cyc/step (measured exactly, r14).
// The compiler's load-at-use schedule IS the optimal software pipeline here —
// every attempt to decouple loads from consumers (LDS split r17, forced-issue
// asm + counted vmcnt r18) measured ~2x WORSE; register residency is
// structurally impossible (256 arch-regs/wave unified file, r2-r15); cross-CU
// split pays ~6x in agent-scope sync (r11). Mask-skip halves the work;
// MFMA does the GEMV under the stream's shadow.
template <typename GiT>
__global__ void
__attribute__((amdgpu_flat_work_group_size(512, 512), amdgpu_waves_per_eu(2, 2)))
gru_scan_mfma(const GiT* __restrict__ gi,          // [T*B][768]
              const int* __restrict__ mask,         // [T*B]
              const float* __restrict__ h0,         // [B][256]
              const unsigned int* __restrict__ wf,  // packed B-fragments
              const float* __restrict__ b_hh,       // [768]
              float* __restrict__ out,              // [T*B][256]
              float* __restrict__ hfin)             // [B][256]
{
    const int b   = blockIdx.x;
    const int tid = threadIdx.x;   // 0..511
    const int wv  = tid >> 6;      // 0..7
    const int l   = tid & 63;

    __shared__ __align__(16) _Float16 hhalf[HH];  // h state, f16
    __shared__ float gh_lds[GG];
    __shared__ int mlds[TT];

    // --- weights: loaded per step by the compiler's load-at-use pipeline ---
    u32x4 w[6][8];
    {
        const u32x4* wp = (const u32x4*)wf;
#pragma unroll
        for (int nt = 0; nt < 6; ++nt)
#pragma unroll
            for (int kt = 0; kt < 8; ++kt)
                w[nt][kt] = wp[(size_t)((wv * 6 + nt) * 8 + kt) * 64 + l];
    }
#pragma unroll
    for (int nt = 0; nt < 6; ++nt)
#pragma unroll
        for (int kt = 0; kt < 8; ++kt)
            asm volatile("" : "+a"(w[nt][kt]));

    for (int i = tid; i < TT; i += 512)
        mlds[i] = mask[i * BB + b];

    float h_r = 0.f, bh0 = 0.f, bh1 = 0.f, bh2 = 0.f;
    if (tid < HH) {
        h_r = h0[b * HH + tid];
        hhalf[tid] = (_Float16)h_r;
        bh0 = b_hh[tid];
        bh1 = b_hh[tid + HH];
        bh2 = b_hh[tid + 2 * HH];
    }
    __syncthreads();

    // A-operand broadcast source: 16-lane group g=(l>>4) reads h[kt*32+g*8..]
    const _Float16* abase = hhalf + (l >> 4) * 8;

    for (int ts = 0; ts < TT; ++ts) {
        if (mlds[ts]) {
            // gi loads first (consumed in the gate phase, ~700 cyc later)
            float ir = 0.f, iz = 0.f, inn = 0.f;
            if (tid < HH) {
                const GiT* gtb = gi + ((size_t)ts * BB + b) * GG;
                ir  = ldgi(gtb + tid);
                iz  = ldgi(gtb + tid + HH);
                inn = ldgi(gtb + tid + 2 * HH);
            }

            // --- GEMV on the matrix pipe: gh[768] = h @ w_hh^T ---
            f32x4 acc[6] = {};
#pragma unroll
            for (int kt = 0; kt < 8; ++kt) {
                f16x8 a = *(const f16x8*)(abase + kt * 32);  // LDS broadcast
#pragma unroll
                for (int nt = 0; nt < 6; ++nt)
                    acc[nt] = __builtin_amdgcn_mfma_f32_16x16x32_f16(
                        a, __builtin_bit_cast(f16x8, w[nt][kt]), acc[nt],
                        0, 0, 0);
            }
            // C row 0 (all rows equal): lanes 0-15, reg 0
            if (l < 16) {
#pragma unroll
                for (int nt = 0; nt < 6; ++nt)
                    gh_lds[wv * 96 + nt * 16 + l] = acc[nt][0];
            }
            __syncthreads();  // gh visible; hhalf reads done

            if (tid < HH) {
                float hr = gh_lds[tid] + bh0;
                float hz = gh_lds[tid + HH] + bh1;
                float hn = gh_lds[tid + 2 * HH] + bh2;
                float r = 1.f / (1.f + __expf(-(ir + hr)));
                float z = 1.f / (1.f + __expf(-(iz + hz)));
                float e = __expf(2.f * (inn + r * hn));
                float n = 1.f - 2.f / (e + 1.f);
                float ht = (1.f - z) * n + z * h_r;
                out[((size_t)ts * BB + b) * HH + tid] = ht;
                h_r = ht;
                hhalf[tid] = (_Float16)ht;
            }
            __syncthreads();  // h update visible before next GEMV
        } else {
            // masked: h unchanged, output row exactly zero; no barriers
            if (tid < HH)
                out[((size_t)ts * BB + b) * HH + tid] = 0.f;
        }
    }
    if (tid < HH) hfin[b * HH + tid] = h_r;
}

extern "C" void kernel_launch(void* const* d_in, const int* in_sizes, int n_in,
                              void* d_out, int out_size, void* d_ws, size_t ws_size,
                              hipStream_t stream) {
    const float* seq  = (const float*)d_in[0];
    const int*   mask = (const int*)  d_in[1];
    const float* h0   = (const float*)d_in[2];
    const float* w_ih = (const float*)d_in[3];
    const float* w_hh = (const float*)d_in[4];
    const float* b_ih = (const float*)d_in[5];
    const float* b_hh = (const float*)d_in[6];

    float* out  = (float*)d_out;
    float* hfin = out + (size_t)TT * BB * HH;

    // workspace layout: [wf: 98304 u32][gi: T*B*768 f32 (or bf16 fallback)]
    const size_t wf_elems = (size_t)128 * GG;  // 98304
    unsigned int* wf = (unsigned int*)d_ws;
    const size_t gi_elems = (size_t)TT * BB * GG;
    const size_t need_f32 = wf_elems * 4 + gi_elems * 4;

    pack_w<<<(int)(wf_elems / 256), 256, 0, stream>>>(w_hh, wf);

    dim3 ggrid(GG / 128, (TT * BB) / 128);  // 6 x 512
    if (ws_size >= need_f32) {
        float* gip = (float*)d_ws + wf_elems;
        gemm_gi_mfma<float><<<ggrid, 256, 0, stream>>>(seq, w_ih, b_ih, gip);
        gru_scan_mfma<float><<<BB, 512, 0, stream>>>(gip, mask, h0, wf, b_hh,
                                                     out, hfin);
    } else {
        __hip_bfloat16* gip = (__hip_bfloat16*)((float*)d_ws + wf_elems);
        gemm_gi_mfma<__hip_bfloat16><<<ggrid, 256, 0, stream>>>(seq, w_ih, b_ih, gip);
        gru_scan_mfma<__hip_bfloat16><<<BB, 512, 0, stream>>>(gip, mask, h0, wf,
                                                              b_hh, out, hfin);
    }
}